// Round 1
// baseline (265.277 us; speedup 1.0000x reference)
//
#include <hip/hip_runtime.h>
#include <hip/hip_bf16.h>

#define B_N 65536
#define D_N 64
#define H_N 128

typedef __attribute__((ext_vector_type(8))) __bf16 bf16x8;
typedef __attribute__((ext_vector_type(8))) unsigned short ushort8;
typedef __attribute__((ext_vector_type(4))) float f32x4;

// ---------- ws layout (bytes) ----------
// 0     : unsigned max|time_delta| bits (atomicMax target; memset to 0 first)
// 64    : WzT  bf16 [128][64]   (us idx 0..8191)      Wz = W1[0:64,:] transposed
// 16448 : W2T  bf16 [128][128]  (us idx 8192..24575)
// 49216 : W3T  bf16 [64][128]   (us idx 24576..32767)

__device__ __forceinline__ unsigned short f2bf(float f) {
    unsigned u = __float_as_uint(f);
    u += 0x7FFFu + ((u >> 16) & 1u);   // RNE
    return (unsigned short)(u >> 16);
}

__device__ __forceinline__ float bf2f(unsigned short s) {
    return __uint_as_float(((unsigned)s) << 16);
}

__device__ __forceinline__ float fast_tanh(float x) {
    // tanh(x) = 1 - 2/(exp(2x)+1); exp->inf => 1, exp->0 => -1 (no NaN paths)
    float e = __expf(2.0f * x);
    return fmaf(-2.0f, __builtin_amdgcn_rcpf(e + 1.0f), 1.0f);
}

// ---------- kernel 1: max|time_delta| ----------
__global__ void k_reduce(const float* __restrict__ td, unsigned* __restrict__ ws) {
    int i = blockIdx.x * blockDim.x + threadIdx.x;
    float m = 0.0f;
    for (; i < B_N; i += gridDim.x * blockDim.x) m = fmaxf(m, fabsf(td[i]));
#pragma unroll
    for (int o = 32; o; o >>= 1) m = fmaxf(m, __shfl_down(m, o));
    if ((threadIdx.x & 63) == 0) atomicMax(ws, __float_as_uint(m));
}

// ---------- kernel 2: transpose weights to bf16 in ws ----------
__global__ void k_prep(const float* __restrict__ W1, const float* __restrict__ W2,
                       const float* __restrict__ W3, unsigned short* __restrict__ wsb) {
    int i = blockIdx.x * blockDim.x + threadIdx.x;
    const int total = 8192 + 16384 + 8192;
    for (; i < total; i += gridDim.x * blockDim.x) {
        float v;
        int o = i;
        if (o < 8192) {                       // WzT[n][k] = W1[k][n], n<128, k<64
            int n = o >> 6, k = o & 63;
            v = W1[k * 128 + n];
        } else if (o < 8192 + 16384) {        // W2T[n][k] = W2[k][n], n<128, k<128
            o -= 8192;
            int n = o >> 7, k = o & 127;
            v = W2[k * 128 + n];
        } else {                              // W3T[n][k] = W3[k][n], n<64, k<128
            o -= 8192 + 16384;
            int n = o >> 7, k = o & 127;
            v = W3[k * 64 + n];
        }
        wsb[i] = f2bf(v);
    }
}

// ---------- kernel 3: the ODE solver ----------
// block = 256 threads = 4 waves; each wave owns 16 rows; grid = 65536/64 = 1024
__launch_bounds__(256, 2)
__global__ void k_main(const float* __restrict__ z_in, const float* __restrict__ td,
                       const float* __restrict__ W1, const float* __restrict__ b1,
                       const float* __restrict__ b2, const float* __restrict__ b3,
                       const void* __restrict__ ws, float* __restrict__ out) {
    // LDS: padded bf16 weights + per-wave scratch.  Pad: stride 72/136 us keeps
    // b128 fragment reads at <=2-way bank aliasing (free, m136).
    __shared__ unsigned short WzL[128 * 72];    // 18432 B
    __shared__ unsigned short W3L[64 * 136];    // 17408 B
    __shared__ unsigned short hS[4][16 * 136];  // 17408 B, per-wave scratch

    const unsigned* wsu = (const unsigned*)ws;
    const unsigned short* wzg = (const unsigned short*)((const char*)ws + 64);
    const unsigned short* w2g = wzg + 8192;
    const unsigned short* w3g = wzg + 24576;

    const int tid = threadIdx.x;

    // stage WzT into LDS (1024 chunks of 16B)
    for (int c = tid; c < 1024; c += 256) {
        int n = c >> 3, k8 = (c & 7) << 3;
        *(ushort8*)&WzL[n * 72 + k8] = *(const ushort8*)&wzg[n * 64 + k8];
    }
    // stage W3T into LDS
    for (int c = tid; c < 1024; c += 256) {
        int n = c >> 4, k8 = (c & 15) << 3;
        *(ushort8*)&W3L[n * 136 + k8] = *(const ushort8*)&w3g[n * 128 + k8];
    }
    __syncthreads();   // only barrier; waves are independent afterwards

    const float maxab = __uint_as_float(wsu[0]);
    const int steps = (int)ceil((double)maxab / 0.1);   // matches np.ceil(float64)

    const int wave = tid >> 6;
    const int lane = tid & 63;
    const int q = lane >> 4;      // quad: selects k-offset in A/B frags, row-group in C
    const int m15 = lane & 15;    // A row / B col / C col
    const int row = blockIdx.x * 64 + wave * 16 + m15;
    unsigned short* hw = hS[wave];

    // z in fp32 registers, A-layout: zr[kt*8+j] = z[row][kt*32 + q*8 + j]
    float zr[16];
#pragma unroll
    for (int kt = 0; kt < 2; ++kt) {
        const float4* p = (const float4*)(z_in + (size_t)row * 64 + kt * 32 + q * 8);
        float4 a = p[0], b = p[1];
        zr[kt * 8 + 0] = a.x; zr[kt * 8 + 1] = a.y; zr[kt * 8 + 2] = a.z; zr[kt * 8 + 3] = a.w;
        zr[kt * 8 + 4] = b.x; zr[kt * 8 + 5] = b.y; zr[kt * 8 + 6] = b.z; zr[kt * 8 + 7] = b.w;
    }
    const float dtr = (steps > 0) ? (td[row] / (float)steps) : 0.0f;

    // W2 B-fragments cached in registers (32 frags * 16B = 128 VGPRs)
    bf16x8 w2f[8][4];
#pragma unroll
    for (int n0 = 0; n0 < 8; ++n0)
#pragma unroll
        for (int kt = 0; kt < 4; ++kt)
            w2f[n0][kt] = __builtin_bit_cast(
                bf16x8, *(const ushort8*)&w2g[(n0 * 16 + m15) * 128 + kt * 32 + q * 8]);

    // per-lane bias registers (col = n0*16 + m15 in C-layout)
    float wtr[8], b1r[8], b2r[8], b3r[4];
#pragma unroll
    for (int n0 = 0; n0 < 8; ++n0) {
        wtr[n0] = W1[64 * 128 + n0 * 16 + m15];   // Wt = last row of W1
        b1r[n0] = b1[n0 * 16 + m15];
        b2r[n0] = b2[n0 * 16 + m15];
    }
#pragma unroll
    for (int n0 = 0; n0 < 4; ++n0) b3r[n0] = b3[n0 * 16 + m15];

    for (int s = 0; s < steps; ++s) {
        const float t = (float)s * 0.1f;

        // ---- layer 1: h1 = tanh(z @ Wz + t*Wt + b1) ----
        bf16x8 zA[2];
#pragma unroll
        for (int kt = 0; kt < 2; ++kt) {
            ushort8 u;
#pragma unroll
            for (int j = 0; j < 8; ++j) u[j] = f2bf(zr[kt * 8 + j]);
            zA[kt] = __builtin_bit_cast(bf16x8, u);
        }
#pragma unroll
        for (int n0 = 0; n0 < 8; ++n0) {
            f32x4 acc = {0.f, 0.f, 0.f, 0.f};
#pragma unroll
            for (int kt = 0; kt < 2; ++kt) {
                bf16x8 bf = __builtin_bit_cast(
                    bf16x8, *(const ushort8*)&WzL[(n0 * 16 + m15) * 72 + kt * 32 + q * 8]);
                acc = __builtin_amdgcn_mfma_f32_16x16x32_bf16(zA[kt], bf, acc, 0, 0, 0);
            }
            const float b1t = fmaf(t, wtr[n0], b1r[n0]);
#pragma unroll
            for (int r = 0; r < 4; ++r)   // C-layout: row q*4+r, col n0*16+m15
                hw[(q * 4 + r) * 136 + n0 * 16 + m15] = f2bf(fast_tanh(acc[r] + b1t));
        }

        // ---- layer 2: h2 = tanh(h1 @ W2 + b2) ----
        bf16x8 hA[4];
#pragma unroll
        for (int kt = 0; kt < 4; ++kt)
            hA[kt] = __builtin_bit_cast(
                bf16x8, *(const ushort8*)&hw[m15 * 136 + kt * 32 + q * 8]);
#pragma unroll
        for (int n0 = 0; n0 < 8; ++n0) {
            f32x4 acc = {0.f, 0.f, 0.f, 0.f};
#pragma unroll
            for (int kt = 0; kt < 4; ++kt)
                acc = __builtin_amdgcn_mfma_f32_16x16x32_bf16(hA[kt], w2f[n0][kt], acc, 0, 0, 0);
#pragma unroll
            for (int r = 0; r < 4; ++r)
                hw[(q * 4 + r) * 136 + n0 * 16 + m15] = f2bf(fast_tanh(acc[r] + b2r[n0]));
        }

        // ---- layer 3: dz = h2 @ W3 + b3 (stored bf16 in scratch) ----
        bf16x8 gA[4];
#pragma unroll
        for (int kt = 0; kt < 4; ++kt)
            gA[kt] = __builtin_bit_cast(
                bf16x8, *(const ushort8*)&hw[m15 * 136 + kt * 32 + q * 8]);
#pragma unroll
        for (int n0 = 0; n0 < 4; ++n0) {
            f32x4 acc = {0.f, 0.f, 0.f, 0.f};
#pragma unroll
            for (int kt = 0; kt < 4; ++kt) {
                bf16x8 bf = __builtin_bit_cast(
                    bf16x8, *(const ushort8*)&W3L[(n0 * 16 + m15) * 136 + kt * 32 + q * 8]);
                acc = __builtin_amdgcn_mfma_f32_16x16x32_bf16(gA[kt], bf, acc, 0, 0, 0);
            }
#pragma unroll
            for (int r = 0; r < 4; ++r)
                hw[(q * 4 + r) * 136 + n0 * 16 + m15] = f2bf(acc[r] + b3r[n0]);
        }

        // ---- z += dz * actual_dt (read dz back in A-layout) ----
#pragma unroll
        for (int kt = 0; kt < 2; ++kt) {
            ushort8 dzb = *(const ushort8*)&hw[m15 * 136 + kt * 32 + q * 8];
#pragma unroll
            for (int j = 0; j < 8; ++j)
                zr[kt * 8 + j] = fmaf(bf2f(dzb[j]), dtr, zr[kt * 8 + j]);
        }
    }

    // store final z
#pragma unroll
    for (int kt = 0; kt < 2; ++kt) {
        float4 a, b;
        a.x = zr[kt * 8 + 0]; a.y = zr[kt * 8 + 1]; a.z = zr[kt * 8 + 2]; a.w = zr[kt * 8 + 3];
        b.x = zr[kt * 8 + 4]; b.y = zr[kt * 8 + 5]; b.z = zr[kt * 8 + 6]; b.w = zr[kt * 8 + 7];
        float4* p = (float4*)(out + (size_t)row * 64 + kt * 32 + q * 8);
        p[0] = a; p[1] = b;
    }
}

extern "C" void kernel_launch(void* const* d_in, const int* in_sizes, int n_in,
                              void* d_out, int out_size, void* d_ws, size_t ws_size,
                              hipStream_t stream) {
    const float* z  = (const float*)d_in[0];
    const float* td = (const float*)d_in[1];
    const float* W1 = (const float*)d_in[2];
    const float* b1 = (const float*)d_in[3];
    const float* W2 = (const float*)d_in[4];
    const float* b2 = (const float*)d_in[5];
    const float* W3 = (const float*)d_in[6];
    const float* b3 = (const float*)d_in[7];
    float* out = (float*)d_out;
    (void)in_sizes; (void)n_in; (void)out_size; (void)ws_size;

    // ws[0] holds the atomicMax target; harness poisons ws with 0xAA each call.
    hipMemsetAsync(d_ws, 0, 64, stream);

    k_reduce<<<64, 256, 0, stream>>>(td, (unsigned*)d_ws);
    k_prep<<<64, 256, 0, stream>>>(W1, W2, W3,
                                   (unsigned short*)((char*)d_ws + 64));
    k_main<<<1024, 256, 0, stream>>>(z, td, W1, b1, b2, b3, d_ws, out);
}